// Round 4
// baseline (335.460 us; speedup 1.0000x reference)
//
#include <hip/hip_runtime.h>
#include <stdint.h>
#include <math.h>

#define T_TOK 512
#define DDIM  2048
#define IDIM  768
#define NEXP  16
#define TOPK  8
#define LDB   72   // LDS B row stride (bf16 units): 64 data + 8 pad

typedef __attribute__((ext_vector_type(8))) short bf16x8;
typedef __attribute__((ext_vector_type(4))) float f32x4;

// ---------- fp8 e4m3fn RTNE quant-dequant (fp32-exact, result fits bf16) ----------
__device__ __forceinline__ float e4m3_rtne(float f) {
  uint32_t u = __float_as_uint(f);
  uint32_t sign = u & 0x80000000u;
  uint32_t a = u & 0x7FFFFFFFu;
  float fa = __uint_as_float(a);
  float out;
  if (fa >= 0.015625f) {            // normal: keep 3 mantissa bits, RTNE
    uint32_t lsb = (a >> 20) & 1u;
    a += 0x0007FFFFu + lsb;
    a &= 0xFFF00000u;
    out = __uint_as_float(a);
  } else {                          // subnormal: quantum 2^-9
    out = rintf(fa * 512.0f) * 0.001953125f;
  }
  return __uint_as_float(__float_as_uint(out) | sign);
}

__global__ void qdq_kernel(const float* __restrict__ x, ushort* __restrict__ xq) {
  int idx = blockIdx.x * 256 + threadIdx.x;
  float v = x[idx];
  float a = fabsf(v);
#pragma unroll
  for (int m = 16; m >= 1; m >>= 1)
    a = fmaxf(a, __shfl_xor(a, m, 32));
  a = fmaxf(a, 1e-4f);
  float scale = a / 448.0f;
  uint32_t b = __float_as_uint(scale);
  uint32_t ex = ((b >> 23) & 255u) + ((b & 0x7FFFFFu) ? 1u : 0u);
  ex = ex < 1u ? 1u : (ex > 254u ? 254u : ex);
  float rscale = __uint_as_float(ex << 23);
  float inv = 1.0f / rscale;
  float r = e4m3_rtne(v * inv) * rscale;       // exactly representable in bf16
  xq[idx] = (ushort)(__float_as_uint(r) >> 16);
}

// ---------- routing ----------
__global__ void route_kernel(const int* __restrict__ ids, const float* __restrict__ wts,
                             int* counts, int* offsets, int* lists, float* combs,
                             int* tpe, int* tps, int* tpn) {
  int t = threadIdx.x;  // 512 threads
  int  myid[TOPK];
  float myw[TOPK];
#pragma unroll
  for (int k = 0; k < TOPK; k++) { myid[k] = ids[t*TOPK+k]; myw[k] = wts[t*TOPK+k]; }
  int np = 0;
  for (int e = 0; e < NEXP; e++) {
    float s = 0.f; bool r = false;
#pragma unroll
    for (int k = 0; k < TOPK; k++) if (myid[k] == e) { s += myw[k]; r = true; }
    if (r) {
      int slot = atomicAdd(&counts[e], 1);
      lists[(e<<9) + slot] = t;
      combs[(e<<9) + slot] = s;
      tpe[t*TOPK + np] = e;
      tps[t*TOPK + np] = slot;
      np++;
    }
  }
  tpn[t] = np;
  __syncthreads();
  if (t == 0) {
    int acc = 0;
    for (int e = 0; e < NEXP; e++) {
      offsets[e] = acc;
      acc += atomicAdd(&counts[e], 0);
    }
    offsets[NEXP] = acc;
  }
}

// ---------- fp4 byte (2 nibbles) -> packed 2x bf16; S = (sf-1)<<1 ----------
__device__ __forceinline__ uint32_t dec2(uint32_t w8, uint32_t S) {
  uint32_t lo = w8 & 15u, hi = (w8 >> 4) & 15u;
  uint32_t mlo = lo & 7u, mhi = hi & 7u;
  uint32_t clo = (mlo < 2u) ? 0u : mlo;
  uint32_t chi = (mhi < 2u) ? 0u : mhi;
  uint32_t blo = (mlo == 0u) ? 0u : ((S + clo) << 6);
  uint32_t bhi = (mhi == 0u) ? 0u : ((S + chi) << 6);
  blo |= (lo & 8u) << 12;
  bhi |= (hi & 8u) << 12;
  return blo | (bhi << 16);
}

// ---------- GEMM1 (bf16 MFMA): M=128 tokens x 32 cols (gate&up), BK=64, 128 thr ----------
__global__ __launch_bounds__(128,2) void gemm1_kernel(
    const ushort* __restrict__ xq, const int* __restrict__ w13,
    const int* __restrict__ w13s, const int* __restrict__ counts,
    const int* __restrict__ offsets, const int* __restrict__ lists,
    const float* __restrict__ combs, ushort* __restrict__ a_buf)
{
  const int e  = blockIdx.x;
  const int i0 = blockIdx.y << 5;     // 32 feature cols (applied to both gate & up)
  const int m0 = blockIdx.z << 7;     // 128 token rows
  const int cnt = counts[e];
  if (m0 >= cnt) return;

  __shared__ __align__(16) ushort Bsh[64*LDB];   // rows 0..31 gate, 32..63 up; 18 KB
  __shared__ int   toks[128];
  __shared__ float cmbs[128];

  const int tid = threadIdx.x;
  { int m = m0 + tid; bool v = m < cnt;
    toks[tid] = v ? lists[(e<<9)+m] : 0;   // clamp to token 0; masked at epilogue
    cmbs[tid] = v ? combs[(e<<9)+m] : 0.f; }
  __syncthreads();

  const int wv = tid >> 6, l = tid & 63, l16 = l & 15, q = l >> 4;

  // A fragment source rows (direct from global; xq is L2-resident)
  const ushort* arow[4];
#pragma unroll
  for (int i = 0; i < 4; i++) {
    int row = wv*64 + i*16 + l16;
    arow[i] = xq + (size_t)toks[row]*DDIM + q*8;
  }

  // B staging: 64 rows x 64 k; thread -> (row rb, k-half hb of 32)
  const int rb = tid >> 1, hb = tid & 1;
  const int feat = (rb < 32) ? (i0 + rb) : (IDIM + i0 + (rb - 32));
  const int* wrow = w13 + ((size_t)e*(2*IDIM) + feat)*(DDIM/2) + hb*16;
  const int* srow = w13s + ((size_t)e*(2*IDIM) + feat)*(DDIM/32);
  ushort* bdst = Bsh + rb*LDB + hb*32;

  f32x4 acc[4][4];
#pragma unroll
  for (int i = 0; i < 4; i++)
#pragma unroll
    for (int j = 0; j < 4; j++) acc[i][j] = (f32x4){0.f,0.f,0.f,0.f};

  for (int k0 = 0; k0 < DDIM; k0 += 64) {
    int4 wq[4];
    const int4* bp = (const int4*)(wrow + (k0 >> 1));
#pragma unroll
    for (int c = 0; c < 4; c++) wq[c] = bp[c];
    uint32_t S = (((uint32_t)srow[(k0 >> 5) + hb]) - 1u) << 1;

    bf16x8 afr[4][2];
#pragma unroll
    for (int i = 0; i < 4; i++)
#pragma unroll
      for (int s = 0; s < 2; s++)
        afr[i][s] = *(const bf16x8*)(arow[i] + k0 + s*32);

    __syncthreads();   // previous iteration's LDS reads complete
    {
      uint32_t od[16];
      const int* wi = (const int*)wq;
#pragma unroll
      for (int c = 0; c < 16; c++) od[c] = dec2((uint32_t)wi[c], S);
#pragma unroll
      for (int c = 0; c < 4; c++)
        *(uint4*)(bdst + c*8) = make_uint4(od[4*c], od[4*c+1], od[4*c+2], od[4*c+3]);
    }
    __syncthreads();

#pragma unroll
    for (int s = 0; s < 2; s++) {
      bf16x8 bfr[4];
#pragma unroll
      for (int j = 0; j < 4; j++)
        bfr[j] = *(const bf16x8*)(Bsh + (j*16 + l16)*LDB + s*32 + q*8);
#pragma unroll
      for (int i = 0; i < 4; i++)
#pragma unroll
        for (int j = 0; j < 4; j++)
          acc[i][j] = __builtin_amdgcn_mfma_f32_16x16x32_bf16(afr[i][s], bfr[j], acc[i][j], 0, 0, 0);
    }
  }

  const int obase = offsets[e];
#pragma unroll
  for (int i = 0; i < 4; i++) {
#pragma unroll
    for (int r = 0; r < 4; r++) {
      int mrow = wv*64 + i*16 + q*4 + r;   // C/D: row=(lane>>4)*4+reg, col=lane&15
      int gm = m0 + mrow;
      if (gm < cnt) {
        float c = cmbs[mrow];
        ushort* dst = a_buf + (size_t)(obase + gm)*IDIM + i0 + l16;
#pragma unroll
        for (int jj = 0; jj < 2; jj++) {
          float g = acc[i][jj][r], u = acc[i][jj+2][r];
          float val = (g / (1.f + expf(-g))) * u * c;   // comb folded (linear downstream)
          uint32_t bb = __float_as_uint(val);
          bb += 0x7FFFu + ((bb >> 16) & 1u);            // RTNE to bf16
          dst[jj*16] = (ushort)(bb >> 16);
        }
      }
    }
  }
}

// ---------- GEMM2 (bf16 MFMA): M=128 rows x 64 d-cols, BK=64, 128 thr ----------
__global__ __launch_bounds__(128,2) void gemm2_kernel(
    const ushort* __restrict__ a_buf, const int* __restrict__ w2,
    const int* __restrict__ w2s, const int* __restrict__ counts,
    const int* __restrict__ offsets, const int* __restrict__ lists,
    float* __restrict__ out, float* __restrict__ ye, int use_ye)
{
  const int e  = blockIdx.x;
  const int n0 = blockIdx.y << 6;     // 64 output cols
  const int m0 = blockIdx.z << 7;     // 128 rows
  const int cnt = counts[e];
  if (m0 >= cnt) return;

  __shared__ __align__(16) ushort Bsh[64*LDB];
  __shared__ int toks[128];

  const int tid = threadIdx.x;
  { int m = m0 + tid; toks[tid] = (m < cnt) ? lists[(e<<9)+m] : -1; }
  __syncthreads();

  const int wv = tid >> 6, l = tid & 63, l16 = l & 15, q = l >> 4;
  const int obase = offsets[e];

  const ushort* arow[4];
#pragma unroll
  for (int i = 0; i < 4; i++) {
    int gm = m0 + wv*64 + i*16 + l16;
    int rowc = (gm < cnt) ? gm : 0;     // clamp; garbage masked at epilogue
    arow[i] = a_buf + (size_t)(obase + rowc)*IDIM + q*8;
  }

  const int rb = tid >> 1, hb = tid & 1;
  const int* wrow = w2 + ((size_t)e*DDIM + n0 + rb)*(IDIM/2) + hb*16;
  const int* srow = w2s + ((size_t)e*DDIM + n0 + rb)*(IDIM/32);
  ushort* bdst = Bsh + rb*LDB + hb*32;

  f32x4 acc[4][4];
#pragma unroll
  for (int i = 0; i < 4; i++)
#pragma unroll
    for (int j = 0; j < 4; j++) acc[i][j] = (f32x4){0.f,0.f,0.f,0.f};

  for (int k0 = 0; k0 < IDIM; k0 += 64) {
    int4 wq[4];
    const int4* bp = (const int4*)(wrow + (k0 >> 1));
#pragma unroll
    for (int c = 0; c < 4; c++) wq[c] = bp[c];
    uint32_t S = (((uint32_t)srow[(k0 >> 5) + hb]) - 1u) << 1;

    bf16x8 afr[4][2];
#pragma unroll
    for (int i = 0; i < 4; i++)
#pragma unroll
      for (int s = 0; s < 2; s++)
        afr[i][s] = *(const bf16x8*)(arow[i] + k0 + s*32);

    __syncthreads();
    {
      uint32_t od[16];
      const int* wi = (const int*)wq;
#pragma unroll
      for (int c = 0; c < 16; c++) od[c] = dec2((uint32_t)wi[c], S);
#pragma unroll
      for (int c = 0; c < 4; c++)
        *(uint4*)(bdst + c*8) = make_uint4(od[4*c], od[4*c+1], od[4*c+2], od[4*c+3]);
    }
    __syncthreads();

#pragma unroll
    for (int s = 0; s < 2; s++) {
      bf16x8 bfr[4];
#pragma unroll
      for (int j = 0; j < 4; j++)
        bfr[j] = *(const bf16x8*)(Bsh + (j*16 + l16)*LDB + s*32 + q*8);
#pragma unroll
      for (int i = 0; i < 4; i++)
#pragma unroll
        for (int j = 0; j < 4; j++)
          acc[i][j] = __builtin_amdgcn_mfma_f32_16x16x32_bf16(afr[i][s], bfr[j], acc[i][j], 0, 0, 0);
    }
  }

#pragma unroll
  for (int i = 0; i < 4; i++) {
#pragma unroll
    for (int r = 0; r < 4; r++) {
      int mrow = wv*64 + i*16 + q*4 + r;
      int gm = m0 + mrow;
      if (gm < cnt) {
        if (use_ye) {
          float* dst = ye + (size_t)(obase + gm)*DDIM + n0 + l16;
#pragma unroll
          for (int j = 0; j < 4; j++) dst[j*16] = acc[i][j][r];
        } else {
          int tok = toks[mrow];
          float* dst = out + (size_t)tok*DDIM + n0 + l16;
#pragma unroll
          for (int j = 0; j < 4; j++) atomicAdd(&dst[j*16], acc[i][j][r]);
        }
      }
    }
  }
}

// ---------- combine ----------
__global__ void combine_kernel(const float* __restrict__ ye, const int* __restrict__ offsets,
                               const int* __restrict__ tpe, const int* __restrict__ tps,
                               const int* __restrict__ tpn, float* __restrict__ out) {
  int t = blockIdx.x;
  int np = tpn[t];
  int rows[TOPK];
#pragma unroll
  for (int j = 0; j < TOPK; j++)
    rows[j] = (j < np) ? (offsets[tpe[t*TOPK+j]] + tps[t*TOPK+j]) : -1;
  for (int c = threadIdx.x; c < DDIM; c += 256) {
    float s = 0.f;
#pragma unroll
    for (int j = 0; j < TOPK; j++)
      if (rows[j] >= 0) s += ye[(size_t)rows[j]*DDIM + c];
    out[(size_t)t*DDIM + c] = s;
  }
}

extern "C" void kernel_launch(void* const* d_in, const int* in_sizes, int n_in,
                              void* d_out, int out_size, void* d_ws, size_t ws_size,
                              hipStream_t stream)
{
  const float* x    = (const float*)d_in[0];
  const float* tw   = (const float*)d_in[1];
  const int*   tids = (const int*)d_in[2];
  const int*   w13  = (const int*)d_in[3];
  const int*   w13s = (const int*)d_in[4];
  const int*   w2   = (const int*)d_in[5];
  const int*   w2s  = (const int*)d_in[6];
  float* out = (float*)d_out;

  char* ws = (char*)d_ws;
  size_t off = 0;
  auto alloc = [&](size_t bytes) { void* p = ws + off; off = (off + bytes + 255) & ~(size_t)255; return p; };
  ushort* xq     = (ushort*)alloc((size_t)T_TOK*DDIM*2);        // 2 MB
  int*   counts  = (int*)alloc(64*4);
  int*   offsets = (int*)alloc(64*4);
  int*   lists   = (int*)alloc((size_t)NEXP*T_TOK*4);
  float* combs   = (float*)alloc((size_t)NEXP*T_TOK*4);
  int*   tpe     = (int*)alloc((size_t)T_TOK*TOPK*4);
  int*   tps     = (int*)alloc((size_t)T_TOK*TOPK*4);
  int*   tpn     = (int*)alloc((size_t)T_TOK*4);
  ushort* a_buf  = (ushort*)alloc((size_t)T_TOK*TOPK*IDIM*2);   // 6 MB
  float* ye      = (float*)(ws + off);
  size_t need_ye = off + (size_t)T_TOK*TOPK*DDIM*4;             // +32 MB
  int use_ye = (ws_size >= need_ye) ? 1 : 0;

  hipMemsetAsync(counts, 0, 256, stream);
  hipMemsetAsync(out, 0, (size_t)out_size * 4, stream);

  qdq_kernel<<<(T_TOK*DDIM)/256, 256, 0, stream>>>(x, xq);
  route_kernel<<<1, T_TOK, 0, stream>>>(tids, tw, counts, offsets, lists, combs, tpe, tps, tpn);
  gemm1_kernel<<<dim3(NEXP, IDIM/32, 4), 128, 0, stream>>>(
      xq, w13, w13s, counts, offsets, lists, combs, a_buf);
  gemm2_kernel<<<dim3(NEXP, DDIM/64, 4), 128, 0, stream>>>(
      a_buf, w2, w2s, counts, offsets, lists, out, ye, use_ye);
  if (use_ye)
    combine_kernel<<<T_TOK, 256, 0, stream>>>(ye, offsets, tpe, tps, tpn, out);
}

// Round 5
// 314.990 us; speedup vs baseline: 1.0650x; 1.0650x over previous
//
#include <hip/hip_runtime.h>
#include <stdint.h>
#include <math.h>

#define T_TOK 512
#define DDIM  2048
#define IDIM  768
#define NEXP  16
#define TOPK  8
#define LDB   72   // LDS B row stride (bf16 units)

typedef __attribute__((ext_vector_type(8))) short bf16x8;
typedef __attribute__((ext_vector_type(4))) float f32x4;

// ---------- fp8 e4m3fn RTNE quant-dequant (fp32-exact, result fits bf16) ----------
__device__ __forceinline__ float e4m3_rtne(float f) {
  uint32_t u = __float_as_uint(f);
  uint32_t sign = u & 0x80000000u;
  uint32_t a = u & 0x7FFFFFFFu;
  float fa = __uint_as_float(a);
  float out;
  if (fa >= 0.015625f) {            // normal: keep 3 mantissa bits, RTNE
    uint32_t lsb = (a >> 20) & 1u;
    a += 0x0007FFFFu + lsb;
    a &= 0xFFF00000u;
    out = __uint_as_float(a);
  } else {                          // subnormal: quantum 2^-9
    out = rintf(fa * 512.0f) * 0.001953125f;
  }
  return __uint_as_float(__float_as_uint(out) | sign);
}

__global__ void qdq_kernel(const float* __restrict__ x, ushort* __restrict__ xq) {
  int idx = blockIdx.x * 256 + threadIdx.x;
  float v = x[idx];
  float a = fabsf(v);
#pragma unroll
  for (int m = 16; m >= 1; m >>= 1)
    a = fmaxf(a, __shfl_xor(a, m, 32));
  a = fmaxf(a, 1e-4f);
  float scale = a / 448.0f;
  uint32_t b = __float_as_uint(scale);
  uint32_t ex = ((b >> 23) & 255u) + ((b & 0x7FFFFFu) ? 1u : 0u);
  ex = ex < 1u ? 1u : (ex > 254u ? 254u : ex);
  float rscale = __uint_as_float(ex << 23);
  float inv = 1.0f / rscale;
  float r = e4m3_rtne(v * inv) * rscale;       // exactly representable in bf16
  xq[idx] = (ushort)(__float_as_uint(r) >> 16);
}

// ---------- routing ----------
__global__ void route_kernel(const int* __restrict__ ids, const float* __restrict__ wts,
                             int* counts, int* offsets, int* lists, float* combs,
                             int* tpe, int* tps, int* tpn) {
  int t = threadIdx.x;  // 512 threads
  int  myid[TOPK];
  float myw[TOPK];
#pragma unroll
  for (int k = 0; k < TOPK; k++) { myid[k] = ids[t*TOPK+k]; myw[k] = wts[t*TOPK+k]; }
  int np = 0;
  for (int e = 0; e < NEXP; e++) {
    float s = 0.f; bool r = false;
#pragma unroll
    for (int k = 0; k < TOPK; k++) if (myid[k] == e) { s += myw[k]; r = true; }
    if (r) {
      int slot = atomicAdd(&counts[e], 1);
      lists[(e<<9) + slot] = t;
      combs[(e<<9) + slot] = s;
      tpe[t*TOPK + np] = e;
      tps[t*TOPK + np] = slot;
      np++;
    }
  }
  tpn[t] = np;
  __syncthreads();
  if (t == 0) {
    int acc = 0;
    for (int e = 0; e < NEXP; e++) {
      offsets[e] = acc;
      acc += atomicAdd(&counts[e], 0);
    }
    offsets[NEXP] = acc;
  }
}

// ---------- fp4 int (1 byte payload = 2 nibbles) -> packed 2x bf16; S = (sf-1)<<1 ----------
__device__ __forceinline__ uint32_t dec2(uint32_t w8, uint32_t S) {
  uint32_t lo = w8 & 15u, hi = (w8 >> 4) & 15u;
  uint32_t mlo = lo & 7u, mhi = hi & 7u;
  uint32_t clo = (mlo < 2u) ? 0u : mlo;
  uint32_t chi = (mhi < 2u) ? 0u : mhi;
  uint32_t blo = (mlo == 0u) ? 0u : ((S + clo) << 6);
  uint32_t bhi = (mhi == 0u) ? 0u : ((S + chi) << 6);
  blo |= (lo & 8u) << 12;
  bhi |= (hi & 8u) << 12;
  return blo | (bhi << 16);
}

// ---------- GEMM1: M=128 (4 waves x 32 rows), N=32 i-cols (gate+up), BK=64, pipelined ----------
__global__ __launch_bounds__(256,3) void gemm1_kernel(
    const ushort* __restrict__ xq, const int* __restrict__ w13,
    const int* __restrict__ w13s, const int* __restrict__ counts,
    const int* __restrict__ offsets, const int* __restrict__ lists,
    const float* __restrict__ combs, ushort* __restrict__ a_buf)
{
  const int e  = blockIdx.x;
  const int i0 = blockIdx.y << 5;
  const int m0 = blockIdx.z << 7;
  const int cnt = counts[e];
  if (m0 >= cnt) return;

  __shared__ __align__(16) ushort Bsh[2][64*LDB];   // 2 x 9 KB double buffer
  __shared__ int   toks[128];
  __shared__ float cmbs[128];

  const int tid = threadIdx.x;
  if (tid < 128) {
    int m = m0 + tid; bool v = m < cnt;
    toks[tid] = v ? lists[(e<<9)+m] : 0;
    cmbs[tid] = v ? combs[(e<<9)+m] : 0.f;
  }
  __syncthreads();

  const int wv = tid >> 6, l = tid & 63, l16 = l & 15, q = l >> 4;

  // A sources: wave wv covers rows wv*32 + i*16 + l16, i<2
  const ushort* arow[2];
#pragma unroll
  for (int i = 0; i < 2; i++)
    arow[i] = xq + (size_t)toks[wv*32 + i*16 + l16]*DDIM + q*8;

  // B staging: 64 rows (32 gate + 32 up) x 64 k per iter; 4 threads/row, 8 ints each
  const int rb = tid >> 2, hq = tid & 3;
  const int feat = (rb < 32) ? (i0 + rb) : (IDIM + i0 + (rb - 32));
  const int* wrow = w13 + ((size_t)e*(2*IDIM) + feat)*(DDIM/2) + hq*8;
  const int* srow = w13s + ((size_t)e*(2*IDIM) + feat)*(DDIM/32) + (hq >> 1);
  const int bdst = rb*LDB + hq*16;

  f32x4 acc[2][4];
#pragma unroll
  for (int i = 0; i < 2; i++)
#pragma unroll
    for (int j = 0; j < 4; j++) acc[i][j] = (f32x4){0.f,0.f,0.f,0.f};

  // ---- prologue: load + dequant iter 0 ----
  bf16x8 afr[2][2];
#pragma unroll
  for (int i = 0; i < 2; i++)
#pragma unroll
    for (int s = 0; s < 2; s++)
      afr[i][s] = *(const bf16x8*)(arow[i] + s*32);
  {
    int4 w0 = *(const int4*)(wrow);
    int4 w1 = *(const int4*)(wrow + 4);
    uint32_t S = (((uint32_t)srow[0]) - 1u) << 1;
    int wi[8] = {w0.x,w0.y,w0.z,w0.w, w1.x,w1.y,w1.z,w1.w};
    uint32_t od[8];
#pragma unroll
    for (int c = 0; c < 8; c++) od[c] = dec2((uint32_t)wi[c], S);
    ushort* d = &Bsh[0][bdst];
    *(uint4*)d       = make_uint4(od[0], od[1], od[2], od[3]);
    *(uint4*)(d + 8) = make_uint4(od[4], od[5], od[6], od[7]);
  }
  __syncthreads();

  for (int k0 = 0; k0 < DDIM; k0 += 64) {
    const int cur = (k0 >> 6) & 1;
    const bool more = (k0 + 64) < DDIM;

    // issue next iter's global loads
    int4 nw0, nw1; uint32_t nS = 0;
    bf16x8 nafr[2][2];
    if (more) {
      const int* wp = wrow + ((k0 + 64) >> 1);
      nw0 = *(const int4*)wp;
      nw1 = *(const int4*)(wp + 4);
      nS = (((uint32_t)srow[(k0 + 64) >> 5]) - 1u) << 1;
#pragma unroll
      for (int i = 0; i < 2; i++)
#pragma unroll
        for (int s = 0; s < 2; s++)
          nafr[i][s] = *(const bf16x8*)(arow[i] + k0 + 64 + s*32);
    }

    // compute current iter
#pragma unroll
    for (int s = 0; s < 2; s++) {
      bf16x8 bfr[4];
#pragma unroll
      for (int j = 0; j < 4; j++)
        bfr[j] = *(const bf16x8*)&Bsh[cur][(j*16 + l16)*LDB + s*32 + q*8];
#pragma unroll
      for (int i = 0; i < 2; i++)
#pragma unroll
        for (int j = 0; j < 4; j++)
          acc[i][j] = __builtin_amdgcn_mfma_f32_16x16x32_bf16(afr[i][s], bfr[j], acc[i][j], 0, 0, 0);
    }

    // dequant next into the other buffer
    if (more) {
      int wi[8] = {nw0.x,nw0.y,nw0.z,nw0.w, nw1.x,nw1.y,nw1.z,nw1.w};
      uint32_t od[8];
#pragma unroll
      for (int c = 0; c < 8; c++) od[c] = dec2((uint32_t)wi[c], nS);
      ushort* d = &Bsh[1 - cur][bdst];
      *(uint4*)d       = make_uint4(od[0], od[1], od[2], od[3]);
      *(uint4*)(d + 8) = make_uint4(od[4], od[5], od[6], od[7]);
#pragma unroll
      for (int i = 0; i < 2; i++)
#pragma unroll
        for (int s = 0; s < 2; s++)
          afr[i][s] = nafr[i][s];
    }
    __syncthreads();
  }

  const int obase = offsets[e];
#pragma unroll
  for (int i = 0; i < 2; i++) {
#pragma unroll
    for (int r = 0; r < 4; r++) {
      int mrow = wv*32 + i*16 + q*4 + r;   // C/D: row=(lane>>4)*4+reg, col=lane&15
      int gm = m0 + mrow;
      if (gm < cnt) {
        float c = cmbs[mrow];
        ushort* dst = a_buf + (size_t)(obase + gm)*IDIM + i0 + l16;
#pragma unroll
        for (int jj = 0; jj < 2; jj++) {
          float g = acc[i][jj][r], u = acc[i][jj+2][r];
          float val = (g / (1.f + expf(-g))) * u * c;   // comb folded (linear downstream)
          uint32_t bb = __float_as_uint(val);
          bb += 0x7FFFu + ((bb >> 16) & 1u);            // RTNE to bf16
          dst[jj*16] = (ushort)(bb >> 16);
        }
      }
    }
  }
}

// ---------- GEMM2: M=128 (4 waves x 32), N=64 d-cols, BK=64, pipelined ----------
__global__ __launch_bounds__(256,3) void gemm2_kernel(
    const ushort* __restrict__ a_buf, const int* __restrict__ w2,
    const int* __restrict__ w2s, const int* __restrict__ counts,
    const int* __restrict__ offsets, const int* __restrict__ lists,
    float* __restrict__ out, ushort* __restrict__ ye, int use_ye)
{
  const int e  = blockIdx.x;
  const int n0 = blockIdx.y << 6;
  const int m0 = blockIdx.z << 7;
  const int cnt = counts[e];
  if (m0 >= cnt) return;

  __shared__ __align__(16) ushort Bsh[2][64*LDB];
  __shared__ int toks[128];

  const int tid = threadIdx.x;
  if (tid < 128) {
    int m = m0 + tid;
    toks[tid] = (m < cnt) ? lists[(e<<9)+m] : -1;
  }
  __syncthreads();

  const int wv = tid >> 6, l = tid & 63, l16 = l & 15, q = l >> 4;
  const int obase = offsets[e];

  const ushort* arow[2];
#pragma unroll
  for (int i = 0; i < 2; i++) {
    int gm = m0 + wv*32 + i*16 + l16;
    int rowc = (gm < cnt) ? gm : 0;
    arow[i] = a_buf + (size_t)(obase + rowc)*IDIM + q*8;
  }

  const int rb = tid >> 2, hq = tid & 3;
  const int* wrow = w2 + ((size_t)e*DDIM + n0 + rb)*(IDIM/2) + hq*8;
  const int* srow = w2s + ((size_t)e*DDIM + n0 + rb)*(IDIM/32) + (hq >> 1);
  const int bdst = rb*LDB + hq*16;

  f32x4 acc[2][4];
#pragma unroll
  for (int i = 0; i < 2; i++)
#pragma unroll
    for (int j = 0; j < 4; j++) acc[i][j] = (f32x4){0.f,0.f,0.f,0.f};

  bf16x8 afr[2][2];
#pragma unroll
  for (int i = 0; i < 2; i++)
#pragma unroll
    for (int s = 0; s < 2; s++)
      afr[i][s] = *(const bf16x8*)(arow[i] + s*32);
  {
    int4 w0 = *(const int4*)(wrow);
    int4 w1 = *(const int4*)(wrow + 4);
    uint32_t S = (((uint32_t)srow[0]) - 1u) << 1;
    int wi[8] = {w0.x,w0.y,w0.z,w0.w, w1.x,w1.y,w1.z,w1.w};
    uint32_t od[8];
#pragma unroll
    for (int c = 0; c < 8; c++) od[c] = dec2((uint32_t)wi[c], S);
    ushort* d = &Bsh[0][bdst];
    *(uint4*)d       = make_uint4(od[0], od[1], od[2], od[3]);
    *(uint4*)(d + 8) = make_uint4(od[4], od[5], od[6], od[7]);
  }
  __syncthreads();

  for (int k0 = 0; k0 < IDIM; k0 += 64) {
    const int cur = (k0 >> 6) & 1;
    const bool more = (k0 + 64) < IDIM;

    int4 nw0, nw1; uint32_t nS = 0;
    bf16x8 nafr[2][2];
    if (more) {
      const int* wp = wrow + ((k0 + 64) >> 1);
      nw0 = *(const int4*)wp;
      nw1 = *(const int4*)(wp + 4);
      nS = (((uint32_t)srow[(k0 + 64) >> 5]) - 1u) << 1;
#pragma unroll
      for (int i = 0; i < 2; i++)
#pragma unroll
        for (int s = 0; s < 2; s++)
          nafr[i][s] = *(const bf16x8*)(arow[i] + k0 + 64 + s*32);
    }

#pragma unroll
    for (int s = 0; s < 2; s++) {
      bf16x8 bfr[4];
#pragma unroll
      for (int j = 0; j < 4; j++)
        bfr[j] = *(const bf16x8*)&Bsh[cur][(j*16 + l16)*LDB + s*32 + q*8];
#pragma unroll
      for (int i = 0; i < 2; i++)
#pragma unroll
        for (int j = 0; j < 4; j++)
          acc[i][j] = __builtin_amdgcn_mfma_f32_16x16x32_bf16(afr[i][s], bfr[j], acc[i][j], 0, 0, 0);
    }

    if (more) {
      int wi[8] = {nw0.x,nw0.y,nw0.z,nw0.w, nw1.x,nw1.y,nw1.z,nw1.w};
      uint32_t od[8];
#pragma unroll
      for (int c = 0; c < 8; c++) od[c] = dec2((uint32_t)wi[c], nS);
      ushort* d = &Bsh[1 - cur][bdst];
      *(uint4*)d       = make_uint4(od[0], od[1], od[2], od[3]);
      *(uint4*)(d + 8) = make_uint4(od[4], od[5], od[6], od[7]);
#pragma unroll
      for (int i = 0; i < 2; i++)
#pragma unroll
        for (int s = 0; s < 2; s++)
          afr[i][s] = nafr[i][s];
    }
    __syncthreads();
  }

#pragma unroll
  for (int i = 0; i < 2; i++) {
#pragma unroll
    for (int r = 0; r < 4; r++) {
      int mrow = wv*32 + i*16 + q*4 + r;
      int gm = m0 + mrow;
      if (gm < cnt) {
        if (use_ye) {
          ushort* dst = ye + (size_t)(obase + gm)*DDIM + n0 + l16;
#pragma unroll
          for (int j = 0; j < 4; j++) {
            uint32_t bb = __float_as_uint(acc[i][j][r]);
            bb += 0x7FFFu + ((bb >> 16) & 1u);
            dst[j*16] = (ushort)(bb >> 16);
          }
        } else {
          int tok = toks[mrow];
          float* dst = out + (size_t)tok*DDIM + n0 + l16;
#pragma unroll
          for (int j = 0; j < 4; j++) atomicAdd(&dst[j*16], acc[i][j][r]);
        }
      }
    }
  }
}

// ---------- combine: out[t,:] = sum of routed ye rows (bf16 -> fp32) ----------
__global__ void combine_kernel(const ushort* __restrict__ ye, const int* __restrict__ offsets,
                               const int* __restrict__ tpe, const int* __restrict__ tps,
                               const int* __restrict__ tpn, float* __restrict__ out) {
  int t = blockIdx.x;
  int np = tpn[t];
  int rows[TOPK];
#pragma unroll
  for (int j = 0; j < TOPK; j++)
    rows[j] = (j < np) ? (offsets[tpe[t*TOPK+j]] + tps[t*TOPK+j]) : -1;
  for (int c = threadIdx.x; c < DDIM; c += 256) {
    float s = 0.f;
#pragma unroll
    for (int j = 0; j < TOPK; j++)
      if (rows[j] >= 0)
        s += __uint_as_float(((uint32_t)ye[(size_t)rows[j]*DDIM + c]) << 16);
    out[(size_t)t*DDIM + c] = s;
  }
}

extern "C" void kernel_launch(void* const* d_in, const int* in_sizes, int n_in,
                              void* d_out, int out_size, void* d_ws, size_t ws_size,
                              hipStream_t stream)
{
  const float* x    = (const float*)d_in[0];
  const float* tw   = (const float*)d_in[1];
  const int*   tids = (const int*)d_in[2];
  const int*   w13  = (const int*)d_in[3];
  const int*   w13s = (const int*)d_in[4];
  const int*   w2   = (const int*)d_in[5];
  const int*   w2s  = (const int*)d_in[6];
  float* out = (float*)d_out;

  char* ws = (char*)d_ws;
  size_t off = 0;
  auto alloc = [&](size_t bytes) { void* p = ws + off; off = (off + bytes + 255) & ~(size_t)255; return p; };
  ushort* xq     = (ushort*)alloc((size_t)T_TOK*DDIM*2);        // 2 MB
  int*   counts  = (int*)alloc(64*4);
  int*   offsets = (int*)alloc(64*4);
  int*   lists   = (int*)alloc((size_t)NEXP*T_TOK*4);
  float* combs   = (float*)alloc((size_t)NEXP*T_TOK*4);
  int*   tpe     = (int*)alloc((size_t)T_TOK*TOPK*4);
  int*   tps     = (int*)alloc((size_t)T_TOK*TOPK*4);
  int*   tpn     = (int*)alloc((size_t)T_TOK*4);
  ushort* a_buf  = (ushort*)alloc((size_t)T_TOK*TOPK*IDIM*2);   // 6 MB
  ushort* ye     = (ushort*)(ws + off);
  size_t need_ye = off + (size_t)T_TOK*TOPK*DDIM*2;             // +16 MB
  int use_ye = (ws_size >= need_ye) ? 1 : 0;

  hipMemsetAsync(counts, 0, 256, stream);
  hipMemsetAsync(out, 0, (size_t)out_size * 4, stream);

  qdq_kernel<<<(T_TOK*DDIM)/256, 256, 0, stream>>>(x, xq);
  route_kernel<<<1, T_TOK, 0, stream>>>(tids, tw, counts, offsets, lists, combs, tpe, tps, tpn);
  gemm1_kernel<<<dim3(NEXP, IDIM/32, 4), 256, 0, stream>>>(
      xq, w13, w13s, counts, offsets, lists, combs, a_buf);
  gemm2_kernel<<<dim3(NEXP, DDIM/64, 4), 256, 0, stream>>>(
      a_buf, w2, w2s, counts, offsets, lists, out, ye, use_ye);
  if (use_ye)
    combine_kernel<<<T_TOK, 256, 0, stream>>>(ye, offsets, tpe, tps, tpn, out);
}